// Round 2
// baseline (1008.148 us; speedup 1.0000x reference)
//
#include <hip/hip_runtime.h>

// convEP: 10-step EP relaxation, MFMA fp16 2-way-split convs (fp32-equivalent).
//   s0' = rho(fc(s1));  s1' = rho(pool(conv0(s2)) + fc^T(s0));  s2' = rho(p2 + convT(unpool(s1, idx1)))
// fp32 x = xh + 2^-12*xl' (fp16 planes, lo pre-scaled 2^12 to stay fp16-normal).
// x*y ~= xh*yh + 2^-12*(xh*yl' + xl'*yh); acc_hi/acc_lo separate, combined at epilogue.
// MFMA 16x16x32_f16: A[m=l16][k=quad*8+j], B[k=quad*8+j][n=l16], C/D: col=l16, row=quad*4+reg.
// R15: pipeline-structure round (R14 VALU cut was neutral -> latency/overhead bound):
//  (a) k_s0fc REMOVED: s0's FC folded into conv0F epilogue. Each thread already loads
//      fcw[k*8192+j] and s1old[j]; accumulate pacc[k] += s1old_j*fcw_kj, wave-reduce,
//      one atomicAdd per wave per k into per-step acc slot s0acc[t+1][b][10].
//      Consumer applies rho(acc+fcb); slot0 prefilled with -fcb so t=0 gives rho(0)=0 exact.
//      Saves 10 serial small dispatches (~80-100 us of mostly-idle GPU).
//  (b) u packed: uh/ul interleaved into u32 [b][pos 256][cp 128] (hi|lo<<16).
//      Epilogue: 8 scattered 4B stores (was 16 scattered 2B). convTg unpacks on stage.
//  (c) s0 snapshot/final via tiny k_s0out (replaces the two s0 memcpys).

typedef _Float16 half8 __attribute__((ext_vector_type(8)));
typedef _Float16 half2v __attribute__((ext_vector_type(2)));
typedef float f32x4 __attribute__((ext_vector_type(4)));
#define MFMA_F16(A, B, C) __builtin_amdgcn_mfma_f32_16x16x32_f16((A), (B), (C), 0, 0, 0)
#define LO_SCALE 2.44140625e-4f   // 2^-12

static __device__ __forceinline__ float rho_(float x) {
  return fminf(fmaxf(x, 0.0f), 1.0f);
}
static __device__ __forceinline__ void split2(float v, _Float16& h, _Float16& l) {
  if (fabsf(v) < 6.1035156e-5f) {
    h = (_Float16)0.f;
    l = (_Float16)(v * 4096.f);
  } else {
    h = (_Float16)v;
    l = (_Float16)((v - (float)h) * 4096.f);
  }
}

// ---------------- K0: one-time weight split+transpose + s0acc init ----------------
// wA0[((tap*2+kc)*128 + co)*32 + cik] = conv0w[co][kc*32+cik][tap]
// wA1[((tap*4+c )*64  + o )*32 + cpk] = conv0w[(c*32+cpk)][o][tap]
// s0acc: 11 slots x [b 64][10]; slot0 = -fcb (so rho(slot0+fcb)=0), slots 1..10 = 0.
__global__ __launch_bounds__(256) void k_wprep(
    const float* __restrict__ w0, const float* __restrict__ fcb,
    _Float16* __restrict__ wA0h, _Float16* __restrict__ wA0l,
    _Float16* __restrict__ wA1h, _Float16* __restrict__ wA1l,
    float* __restrict__ s0acc) {
  int i = blockIdx.x * 256 + threadIdx.x;
  if (i >= 204800) return;
  if (i < 7040) {
    int k = i - (i / 10) * 10;
    s0acc[i] = (i < 640) ? -fcb[k] : 0.f;
  }
  {
    int cik = i & 31, t1 = i >> 5;
    int co = t1 & 127, t2 = t1 >> 7;
    int ck = t2 & 1, tap = t2 >> 1;
    float v = w0[(co * 64 + ck * 32 + cik) * 25 + tap];
    _Float16 h, l; split2(v, h, l);
    wA0h[i] = h; wA0l[i] = l;
  }
  {
    int cpk = i & 31, t1 = i >> 5;
    int o = t1 & 63, t2 = t1 >> 6;
    int c = t2 & 3, tap = t2 >> 2;
    float v = w0[((c * 32 + cpk) * 64 + o) * 25 + tap];
    _Float16 h, l; split2(v, h, l);
    wA1h[i] = h; wA1l[i] = l;
  }
}

// ---------------- K1: p2 = maxpool2x2(conv2d(data, conv1_w) + conv1_b) (once, fp32) ----------------
__global__ __launch_bounds__(256) void k_p2(
    const float* __restrict__ data, const float* __restrict__ w,
    const float* __restrict__ bias, float* __restrict__ p2) {
  __shared__ float ld[3][36][36];
  __shared__ float lw[16][80];
  __shared__ float lb[16];
  int b = blockIdx.x, cg = blockIdx.y, tid = threadIdx.x;
  for (int i = tid; i < 3 * 36 * 36; i += 256) {
    int ci = i / 1296, rem = i % 1296, y = rem / 36, x = rem % 36;
    int gy = y - 2, gx = x - 2;
    float v = 0.f;
    if (gy >= 0 && gy < 32 && gx >= 0 && gx < 32)
      v = data[(b * 3 + ci) * 1024 + gy * 32 + gx];
    ld[ci][y][x] = v;
  }
  for (int i = tid; i < 16 * 75; i += 256) {
    int co = i / 75, k = i % 75;
    lw[co][k] = w[(cg * 16 + co) * 75 + k];
  }
  if (tid < 16) lb[tid] = bias[cg * 16 + tid];
  __syncthreads();
  int ph = tid >> 4, pw = tid & 15;
  int ry = 2 * ph, rx = 2 * pw;
  for (int co = 0; co < 16; co++) {
    float bv = lb[co];
    float a00 = bv, a01 = bv, a10 = bv, a11 = bv;
    for (int ci = 0; ci < 3; ci++) {
#pragma unroll
      for (int ky = 0; ky < 5; ky++) {
#pragma unroll
        for (int kx = 0; kx < 5; kx++) {
          float wv = lw[co][(ci * 5 + ky) * 5 + kx];
          a00 += wv * ld[ci][ry + ky][rx + kx];
          a01 += wv * ld[ci][ry + ky][rx + kx + 1];
          a10 += wv * ld[ci][ry + ky + 1][rx + kx];
          a11 += wv * ld[ci][ry + ky + 1][rx + kx + 1];
        }
      }
    }
    float m = fmaxf(fmaxf(a00, a01), fmaxf(a10, a11));
    p2[((b * 64 + cg * 16 + co) * 16 + ph) * 16 + pw] = m;
  }
}

// ---------------- K2: conv0 (y-half) + pool/argmax + s1 update + u write + s0 FC partial ----------------
// grid (64 b, 4 cg, 2 yh) = 512 blocks, 512 thr = 8 waves = kc(2) x qh(4).
// Wave: m=2 mt (cg's 32 co), n=2 nt (rows qh*2+nt of this y-half), K=32 (kc), all 25 taps.
// Staging: 12-row halo slab (rows yh*8-2..+9, y-pad baked in) of s2_t where
// s2_t = rho(p2 + sum 4 P1 partials) fused (t>0) or s2init (t=0).
// x-halo via zero row at pos 192 (single cndmask on pos; broadcast read).
// LDS plane = 193 rows x 72 ci-pitch; hi at 0, lo at 13896 halfs. Total 55584 B.
// s0 path: s0l = rho(s0prev+fcb) (top-down term); pacc[k] += s1old_j*fcw_kj reusing
// the epilogue's fcw loads; wave-reduced and atomicAdd'ed into s0cur[b][10].
__global__ __launch_bounds__(512, 4) void k_conv0F(
    const float* __restrict__ s2init, const float* __restrict__ p2,
    const float* __restrict__ P1, int fused,
    const _Float16* __restrict__ wA0h, const _Float16* __restrict__ wA0l,
    const float* __restrict__ b0,
    const float* __restrict__ s1old,
    const float* __restrict__ s0prev, float* __restrict__ s0cur,
    const float* __restrict__ fcb,
    const float* __restrict__ fcw, float* __restrict__ s1new,
    unsigned* __restrict__ u) {
  __shared__ __align__(16) _Float16 sm[27792];   // 2 planes x [pos 193][ci 72] = 55584 B
  __shared__ float s0l[10];
  int b = blockIdx.x, cg = blockIdx.y, yh = blockIdx.z, tid = threadIdx.x;

  if (tid < 10) s0l[tid] = rho_(s0prev[b * 10 + tid] + fcb[tid]);

  // stage 12-row slab: pos = ly*16+lx (ly 0..11 -> gy = yh*8-2+ly), 64 ci
  for (int i = tid; i < 12288; i += 512) {
    int ci = i / 192;
    int pos = i - ci * 192;
    int ly = pos >> 4, lx = pos & 15;
    int gy = yh * 8 - 2 + ly;
    float v = 0.f;
    if (gy >= 0 && gy < 16) {
      int gi = b * 16384 + ci * 256 + gy * 16 + lx;
      if (fused) {
        v = rho_(p2[gi] + P1[gi] + P1[gi + 1048576] + P1[gi + 2097152] + P1[gi + 3145728]);
      } else {
        v = s2init[gi];
      }
    }
    _Float16 h, l; split2(v, h, l);
    sm[pos * 72 + ci] = h;
    sm[13896 + pos * 72 + ci] = l;
  }
  // zero row (pos 192) in both planes: oob B-reads land here
  if (tid < 72) {
    sm[13824 + tid] = (_Float16)0.f;           // hi plane, pos 192
    sm[13896 + 13824 + tid] = (_Float16)0.f;   // lo plane, pos 192
  }
  __syncthreads();

  int lane = tid & 63, w = tid >> 6;
  int kc = w & 1, qh = w >> 1;
  int l16 = lane & 15, quad = lane >> 4;   // l16 = x within row

  f32x4 acch[2][2], accl[2][2];   // [nt][mt]
#pragma unroll
  for (int nt = 0; nt < 2; nt++)
#pragma unroll
    for (int mt = 0; mt < 2; mt++) {
      f32x4 z; z[0] = 0.f; z[1] = 0.f; z[2] = 0.f; z[3] = 0.f;
      accl[nt][mt] = z;
      if (kc == 0) {   // bias enters exactly once (kc=0 partial)
        int cb = cg * 32 + mt * 16 + quad * 4;
        f32x4 bi; bi[0] = b0[cb]; bi[1] = b0[cb + 1]; bi[2] = b0[cb + 2]; bi[3] = b0[cb + 3];
        acch[nt][mt] = bi;
      } else {
        acch[nt][mt] = z;
      }
    }

  const int bofs = kc * 32 + quad * 8;
  const int row0 = qh * 2 * 16;
  const int Abase = (kc * 128 + cg * 32 + l16) * 32 + quad * 8;

  half8 ahc[2], alc[2];
#pragma unroll
  for (int mt = 0; mt < 2; mt++)
    ahc[mt] = *(const half8*)(wA0h + Abase + mt * 512);

  for (int tap = 0; tap < 25; tap++) {
    // lo-plane A for this tap (first use is the 2nd MFMA; LDS wait covers it)
#pragma unroll
    for (int mt = 0; mt < 2; mt++)
      alc[mt] = *(const half8*)(wA0l + Abase + tap * 8192 + mt * 512);
    // prefetch next tap's hi-plane A (double-buffer across taps)
    half8 ahn[2];
    {
      int tn = (tap < 24) ? tap + 1 : tap;
#pragma unroll
      for (int mt = 0; mt < 2; mt++)
        ahn[mt] = *(const half8*)(wA0h + Abase + tn * 8192 + mt * 512);
    }
    int ky = tap / 5, kx = tap % 5;          // loop-uniform -> scalar
    int ix = l16 + kx - 2;
    bool oob = ((unsigned)ix > 15u);
    int ptap = ky * 16 + ix;
#pragma unroll
    for (int nt = 0; nt < 2; nt++) {
      int pos = row0 + nt * 16 + ptap;       // y-pad baked into slab
      if (oob) pos = 192;                    // zero row (broadcast read)
      const _Float16* bp = sm + pos * 72 + bofs;
      half8 bh = *(const half8*)bp;
      half8 bl = *(const half8*)(bp + 13896);
#pragma unroll
      for (int mt = 0; mt < 2; mt++) {
        acch[nt][mt] = MFMA_F16(ahc[mt], bh, acch[nt][mt]);
        accl[nt][mt] = MFMA_F16(alc[mt], bh, accl[nt][mt]);
        accl[nt][mt] = MFMA_F16(ahc[mt], bl, accl[nt][mt]);
      }
    }
#pragma unroll
    for (int mt = 0; mt < 2; mt++) ahc[mt] = ahn[mt];
  }

  // kc-combine via LDS C [co 32][130] (16640 B, reuses sm)
  __syncthreads();
  float* C = (float*)sm;
  if (kc == 0) {
#pragma unroll
    for (int nt = 0; nt < 2; nt++) {
      int pos = (qh * 2 + nt) * 16 + l16;   // 0..127 within half
#pragma unroll
      for (int mt = 0; mt < 2; mt++)
#pragma unroll
        for (int r = 0; r < 4; r++)
          C[(mt * 16 + quad * 4 + r) * 130 + pos] = acch[nt][mt][r] + LO_SCALE * accl[nt][mt][r];
    }
  }
  __syncthreads();
  if (kc == 1) {
#pragma unroll
    for (int nt = 0; nt < 2; nt++) {
      int pos = (qh * 2 + nt) * 16 + l16;
#pragma unroll
      for (int mt = 0; mt < 2; mt++)
#pragma unroll
        for (int r = 0; r < 4; r++) {
          int a = (mt * 16 + quad * 4 + r) * 130 + pos;
          C[a] += acch[nt][mt][r] + LO_SCALE * accl[nt][mt][r];
        }
    }
  }
  __syncthreads();

  // epilogue: 32 co x 32 windows (pooled rows yh*4..yh*4+3)
  float pacc[10];
#pragma unroll
  for (int k = 0; k < 10; k++) pacc[k] = 0.f;

  for (int it = 0; it < 2; it++) {
    int idx = it * 512 + tid;          // 1024 = 32 co x 32 windows
    int co = idx >> 5, win = idx & 31;
    int phl = win >> 3, pw = win & 7;
    int p0 = phl * 32 + pw * 2;
    float v0 = C[co * 130 + p0];
    float v1 = C[co * 130 + p0 + 1];
    float v2 = C[co * 130 + p0 + 16];
    float v3 = C[co * 130 + p0 + 17];
    float m0 = v0; int id = 0;
    if (v1 > m0) { m0 = v1; id = 1; }
    if (v2 > m0) { m0 = v2; id = 2; }
    if (v3 > m0) { m0 = v3; id = 3; }
    int co_g = cg * 32 + co;
    int ph = yh * 4 + phl;
    int j = co_g * 64 + ph * 8 + pw;
    float sv = s1old[b * 8192 + j];
    float a = m0;
#pragma unroll
    for (int k = 0; k < 10; k++) {
      float wv = fcw[k * 8192 + j];
      a += s0l[k] * wv;
      pacc[k] += sv * wv;      // s0 FC partial (reuses the fcw load)
    }
    s1new[b * 8192 + j] = rho_(a);
    _Float16 hh, hl; split2(sv, hh, hl);
    half2v hv; hv[0] = hh; hv[1] = hl;
    unsigned pk = __builtin_bit_cast(unsigned, hv);
    int bu = (b * 256 + ph * 32 + pw * 2) * 128 + co_g;   // u32 units: [b][pos 256][cp 128]
    u[bu]        = (id == 0) ? pk : 0u;
    u[bu + 128]  = (id == 1) ? pk : 0u;
    u[bu + 2048] = (id == 2) ? pk : 0u;
    u[bu + 2176] = (id == 3) ? pk : 0u;
  }

  // s0 partial: wave butterfly reduce, one atomic per wave per k
#pragma unroll
  for (int k = 0; k < 10; k++) {
    float v = pacc[k];
#pragma unroll
    for (int off = 32; off > 0; off >>= 1) v += __shfl_xor(v, off);
    if (lane == 0) atomicAdd(&s0cur[b * 10 + k], v);
  }
}

// ---------------- K3: convT GEMM (cp-half x o-half x tap-group partial) ----------------
// zero row at pos 256 (both planes); A hi-plane double-buffered across taps.
// u staged packed (hi|lo u32): 1 coalesced load + 2 b16 LDS writes per element.
__global__ __launch_bounds__(512, 4) void k_convTg(
    const unsigned* __restrict__ u,
    const _Float16* __restrict__ wA1h, const _Float16* __restrict__ wA1l,
    float* __restrict__ P1) {
  __shared__ __align__(16) _Float16 sm[37008];
  int b = blockIdx.x, tid = threadIdx.x;
  int ks = blockIdx.y & 1;
  int oh = blockIdx.y >> 1;
  int tg = blockIdx.z;

  for (int i = tid; i < 16384; i += 512) {
    int pos = i >> 6, c = i & 63;
    unsigned v = u[b * 32768 + pos * 128 + ks * 64 + c];
    half2v hv = __builtin_bit_cast(half2v, v);
    sm[pos * 72 + c] = hv[0];
    sm[18504 + pos * 72 + c] = hv[1];
  }
  if (tid < 72) {
    sm[18432 + tid] = (_Float16)0.f;            // hi plane, pos 256
    sm[18504 + 18432 + tid] = (_Float16)0.f;    // lo plane, pos 256
  }
  __syncthreads();

  int lane = tid & 63, w = tid >> 6;
  int kc = w & 1, qh = w >> 1;
  int l16 = lane & 15, quad = lane >> 4;
  int wy = (l16 >> 1) & 1;
  int x_l = ((l16 >> 2) << 1) + (l16 & 1);

  f32x4 acch[4][2], accl[4][2];
#pragma unroll
  for (int nt = 0; nt < 4; nt++)
#pragma unroll
    for (int mt = 0; mt < 2; mt++) {
      f32x4 z; z[0] = 0.f; z[1] = 0.f; z[2] = 0.f; z[3] = 0.f;
      acch[nt][mt] = z; accl[nt][mt] = z;
    }

  const int bofs = kc * 32 + quad * 8;
  const int Abase = ((ks * 2 + kc) * 64 + oh * 32 + l16) * 32 + quad * 8;

  int yb[4], xb[4];   // loop-invariant spatial bases (+2 conv offset folded in)
#pragma unroll
  for (int nt = 0; nt < 4; nt++) {
    yb[nt] = qh * 4 + (nt >> 1) * 2 + wy + 2;
    xb[nt] = (nt & 1) * 8 + x_l + 2;
  }

  int tap0 = tg * 13, tap1 = tg ? 25 : 13;
  half8 ahc[2], alc[2];
#pragma unroll
  for (int mt = 0; mt < 2; mt++)
    ahc[mt] = *(const half8*)(wA1h + Abase + tap0 * 8192 + mt * 512);

  for (int tap = tap0; tap < tap1; tap++) {
#pragma unroll
    for (int mt = 0; mt < 2; mt++)
      alc[mt] = *(const half8*)(wA1l + Abase + tap * 8192 + mt * 512);
    half8 ahn[2];
    {
      int tn = (tap + 1 < tap1) ? tap + 1 : tap;
#pragma unroll
      for (int mt = 0; mt < 2; mt++)
        ahn[mt] = *(const half8*)(wA1h + Abase + tn * 8192 + mt * 512);
    }
    int ky = tap / 5, kx = tap % 5;
#pragma unroll
    for (int nt = 0; nt < 4; nt++) {
      int iy = yb[nt] - ky, ix = xb[nt] - kx;
      bool oob = ((unsigned)iy > 15u) || ((unsigned)ix > 15u);
      int pos = iy * 16 + ix;
      if (oob) pos = 256;                     // zero row (broadcast read)
      const _Float16* bp = sm + pos * 72 + bofs;
      half8 bh = *(const half8*)bp;
      half8 bl = *(const half8*)(bp + 18504);
#pragma unroll
      for (int mt = 0; mt < 2; mt++) {
        acch[nt][mt] = MFMA_F16(ahc[mt], bh, acch[nt][mt]);
        accl[nt][mt] = MFMA_F16(alc[mt], bh, accl[nt][mt]);
        accl[nt][mt] = MFMA_F16(ahc[mt], bl, accl[nt][mt]);
      }
    }
#pragma unroll
    for (int mt = 0; mt < 2; mt++) ahc[mt] = ahn[mt];
  }

  __syncthreads();
  float* C = (float*)sm;   // [o 32][260]
  if (kc == 0) {
#pragma unroll
    for (int nt = 0; nt < 4; nt++) {
      int pos = (qh * 4 + (nt >> 1) * 2 + wy) * 16 + (nt & 1) * 8 + x_l;
#pragma unroll
      for (int mt = 0; mt < 2; mt++)
#pragma unroll
        for (int r = 0; r < 4; r++)
          C[(mt * 16 + quad * 4 + r) * 260 + pos] = acch[nt][mt][r] + LO_SCALE * accl[nt][mt][r];
    }
  }
  __syncthreads();
  if (kc == 1) {
#pragma unroll
    for (int nt = 0; nt < 4; nt++) {
      int pos = (qh * 4 + (nt >> 1) * 2 + wy) * 16 + (nt & 1) * 8 + x_l;
#pragma unroll
      for (int mt = 0; mt < 2; mt++)
#pragma unroll
        for (int r = 0; r < 4; r++) {
          int a = (mt * 16 + quad * 4 + r) * 260 + pos;
          C[a] += acch[nt][mt][r] + LO_SCALE * accl[nt][mt][r];
        }
    }
  }
  __syncthreads();

  float* op = P1 + (tg * 2 + ks) * 1048576 + (b * 64 + oh * 32) * 256;
  for (int m = tid; m < 8192; m += 512) {
    int o = m >> 8, pos = m & 255;
    op[o * 256 + pos] = C[o * 260 + pos];
  }
}

// ---------------- K3b: out = rho(p2 + P1[0..3])  (only at t=6 snapshot and t=9 final) ----------------
__global__ __launch_bounds__(256) void k_cTcomb(
    const float* __restrict__ p2, const float* __restrict__ P1,
    float* __restrict__ outv) {
  int i = blockIdx.x * 256 + threadIdx.x;   // over 262144 float4s
  float4 p = ((const float4*)p2)[i];
  float4 a0 = ((const float4*)P1)[i];
  float4 a1 = ((const float4*)(P1 + 1048576))[i];
  float4 a2 = ((const float4*)(P1 + 2097152))[i];
  float4 a3 = ((const float4*)(P1 + 3145728))[i];
  float4 o;
  o.x = rho_(p.x + a0.x + a1.x + a2.x + a3.x);
  o.y = rho_(p.y + a0.y + a1.y + a2.y + a3.y);
  o.z = rho_(p.z + a0.z + a1.z + a2.z + a3.z);
  o.w = rho_(p.w + a0.w + a1.w + a2.w + a3.w);
  ((float4*)outv)[i] = o;
}

// ---------------- K4: s0 finalize: out = rho(acc + fcb) (t=6 snapshot, t=9 final) ----------------
__global__ __launch_bounds__(64) void k_s0out(
    const float* __restrict__ acc, const float* __restrict__ fcb,
    float* __restrict__ outv) {
  int i = blockIdx.x * 64 + threadIdx.x;   // 640
  int k = i - (i / 10) * 10;
  outv[i] = rho_(acc[i] + fcb[k]);
}

extern "C" void kernel_launch(void* const* d_in, const int* in_sizes, int n_in,
                              void* d_out, int out_size, void* d_ws, size_t ws_size,
                              hipStream_t stream) {
  const float* data   = (const float*)d_in[0];
  const float* s0init = (const float*)d_in[1];   // zeros
  const float* s1init = (const float*)d_in[2];   // zeros
  const float* s2init = (const float*)d_in[3];   // zeros (t=0 conv0 input)
  const float* conv0w = (const float*)d_in[4];
  const float* conv0b = (const float*)d_in[5];
  const float* conv1w = (const float*)d_in[6];
  const float* conv1b = (const float*)d_in[7];
  const float* fcw    = (const float*)d_in[8];
  const float* fcb    = (const float*)d_in[9];
  (void)s0init;

  // workspace (~35 MB)
  float* p = (float*)d_ws;
  float* s0acc = p;                          p += 7040;      // 11 slots x [64][10]
  float* s1buf[2] = {p, p + 524288};         p += 1048576;
  float* p2 = p;                             p += 1048576;
  float* P1 = p;                             p += 4194304;   // 4 x 1M convT partials
  unsigned* u = (unsigned*)p;                p += 2097152;   // packed hi|lo [b][pos 256][cp 128]
  _Float16* hq = (_Float16*)p;
  _Float16* wA0h = hq;                       hq += 204800;
  _Float16* wA0l = hq;                       hq += 204800;
  _Float16* wA1h = hq;                       hq += 204800;
  _Float16* wA1l = hq;                       hq += 204800;

  k_wprep<<<800, 256, 0, stream>>>(conv0w, fcb, wA0h, wA0l, wA1h, wA1l, s0acc);
  k_p2<<<dim3(64, 4), 256, 0, stream>>>(data, conv1w, conv1b, p2);

  const float* s1o = s1init;
  float* outp = (float*)d_out;

  for (int t = 0; t < 10; t++) {
    int nb = t & 1;
    float* s1w = s1buf[nb];

    // conv0(s2_t) [s2_t = rho(p2+sumP1) fused for t>0] + pool/argmax;
    // s1_new = rho(p1 + fc^T(s0_t)); u = split(unpool(s1_old, idx));
    // s0 FC partials accumulated into s0acc[t+1] (s0_{t+1} = rho(acc + fcb))
    k_conv0F<<<dim3(64, 4, 2), 512, 0, stream>>>(s2init, p2, P1, (t > 0),
                                                 wA0h, wA0l, conv0b,
                                                 s1o,
                                                 s0acc + t * 640, s0acc + (t + 1) * 640,
                                                 fcb, fcw, s1w, u);
    // convT partials (consumed by next step's conv0F staging, or cTcomb at t=6/9)
    k_convTg<<<dim3(64, 4, 2), 512, 0, stream>>>(u, wA1h, wA1l, P1);

    s1o = s1w;

    if (t == 6) {   // PRED_T snapshot (post-update states); s2_7 = rho(p2+sumP1) -> d_out directly
      k_s0out<<<10, 64, 0, stream>>>(s0acc + 7 * 640, fcb, outp + 1573504);
      hipMemcpyAsync(outp + 1574144, s1o, 524288 * sizeof(float), hipMemcpyDeviceToDevice, stream);
      k_cTcomb<<<1024, 256, 0, stream>>>(p2, P1, outp + 2098432);
    }
  }

  // final states: s0_10, s1_10; s2_10 materialized straight into d_out
  k_s0out<<<10, 64, 0, stream>>>(s0acc + 10 * 640, fcb, outp + 0);
  hipMemcpyAsync(outp + 640, s1o, 524288 * sizeof(float), hipMemcpyDeviceToDevice, stream);
  k_cTcomb<<<1024, 256, 0, stream>>>(p2, P1, outp + 524928);
}

// Round 3
// 731.188 us; speedup vs baseline: 1.3788x; 1.3788x over previous
//
#include <hip/hip_runtime.h>

// convEP: 10-step EP relaxation, MFMA fp16 2-way-split convs (fp32-equivalent).
//   s0' = rho(fc(s1));  s1' = rho(pool(conv0(s2)) + fc^T(s0));  s2' = rho(p2 + convT(unpool(s1, idx1)))
// fp32 x = xh + 2^-12*xl' (fp16 planes, lo pre-scaled 2^12 to stay fp16-normal).
// x*y ~= xh*yh + 2^-12*(xh*yl' + xl'*yh); acc_hi/acc_lo separate, combined at epilogue.
// MFMA 16x16x32_f16: A[m=l16][k=quad*8+j], B[k=quad*8+j][n=l16], C/D: col=l16, row=quad*4+reg.
// R16: fix R15's regression (global-atomic s0 reduction = 64-deep RMW chain per address,
// ~+18us/dispatch on conv0F):
//  (a) atomic-free s0 path: wave butterfly -> LDS s0red[8][10] -> 10 plain stores/block
//      into s0part[buf][slot=cg*2+yh][b][10], double-buffered by step parity.
//      Consumer (next conv0F, tid<10) sums 8 slots + fcb; latency hidden (used in epilogue).
//  (b) convTg staging: uint2 load + shift/or unpack + 2 ds_write_b32 (R14 op-count,
//      half the global loads).
//  (c) k_cTcomb absorbs s0 finalize + s1 copy (grid 1536) -> no memcpys/extra dispatches.

typedef _Float16 half8 __attribute__((ext_vector_type(8)));
typedef _Float16 half2v __attribute__((ext_vector_type(2)));
typedef float f32x4 __attribute__((ext_vector_type(4)));
#define MFMA_F16(A, B, C) __builtin_amdgcn_mfma_f32_16x16x32_f16((A), (B), (C), 0, 0, 0)
#define LO_SCALE 2.44140625e-4f   // 2^-12

static __device__ __forceinline__ float rho_(float x) {
  return fminf(fmaxf(x, 0.0f), 1.0f);
}
static __device__ __forceinline__ void split2(float v, _Float16& h, _Float16& l) {
  if (fabsf(v) < 6.1035156e-5f) {
    h = (_Float16)0.f;
    l = (_Float16)(v * 4096.f);
  } else {
    h = (_Float16)v;
    l = (_Float16)((v - (float)h) * 4096.f);
  }
}

// ---------------- K0: one-time weight split+transpose + s0part init ----------------
// wA0[((tap*2+kc)*128 + co)*32 + cik] = conv0w[co][kc*32+cik][tap]
// wA1[((tap*4+c )*64  + o )*32 + cpk] = conv0w[(c*32+cpk)][o][tap]
// s0part: 2 bufs x [slot 8][b 64][10]; buf0 slot0 = -fcb (so rho(sum+fcb)=0 at t=0), rest 0.
__global__ __launch_bounds__(256) void k_wprep(
    const float* __restrict__ w0, const float* __restrict__ fcb,
    _Float16* __restrict__ wA0h, _Float16* __restrict__ wA0l,
    _Float16* __restrict__ wA1h, _Float16* __restrict__ wA1l,
    float* __restrict__ s0part) {
  int i = blockIdx.x * 256 + threadIdx.x;
  if (i >= 204800) return;
  if (i < 10240) {
    int k = i - (i / 10) * 10;
    s0part[i] = (i < 640) ? -fcb[k] : 0.f;
  }
  {
    int cik = i & 31, t1 = i >> 5;
    int co = t1 & 127, t2 = t1 >> 7;
    int ck = t2 & 1, tap = t2 >> 1;
    float v = w0[(co * 64 + ck * 32 + cik) * 25 + tap];
    _Float16 h, l; split2(v, h, l);
    wA0h[i] = h; wA0l[i] = l;
  }
  {
    int cpk = i & 31, t1 = i >> 5;
    int o = t1 & 63, t2 = t1 >> 6;
    int c = t2 & 3, tap = t2 >> 2;
    float v = w0[((c * 32 + cpk) * 64 + o) * 25 + tap];
    _Float16 h, l; split2(v, h, l);
    wA1h[i] = h; wA1l[i] = l;
  }
}

// ---------------- K1: p2 = maxpool2x2(conv2d(data, conv1_w) + conv1_b) (once, fp32) ----------------
__global__ __launch_bounds__(256) void k_p2(
    const float* __restrict__ data, const float* __restrict__ w,
    const float* __restrict__ bias, float* __restrict__ p2) {
  __shared__ float ld[3][36][36];
  __shared__ float lw[16][80];
  __shared__ float lb[16];
  int b = blockIdx.x, cg = blockIdx.y, tid = threadIdx.x;
  for (int i = tid; i < 3 * 36 * 36; i += 256) {
    int ci = i / 1296, rem = i % 1296, y = rem / 36, x = rem % 36;
    int gy = y - 2, gx = x - 2;
    float v = 0.f;
    if (gy >= 0 && gy < 32 && gx >= 0 && gx < 32)
      v = data[(b * 3 + ci) * 1024 + gy * 32 + gx];
    ld[ci][y][x] = v;
  }
  for (int i = tid; i < 16 * 75; i += 256) {
    int co = i / 75, k = i % 75;
    lw[co][k] = w[(cg * 16 + co) * 75 + k];
  }
  if (tid < 16) lb[tid] = bias[cg * 16 + tid];
  __syncthreads();
  int ph = tid >> 4, pw = tid & 15;
  int ry = 2 * ph, rx = 2 * pw;
  for (int co = 0; co < 16; co++) {
    float bv = lb[co];
    float a00 = bv, a01 = bv, a10 = bv, a11 = bv;
    for (int ci = 0; ci < 3; ci++) {
#pragma unroll
      for (int ky = 0; ky < 5; ky++) {
#pragma unroll
        for (int kx = 0; kx < 5; kx++) {
          float wv = lw[co][(ci * 5 + ky) * 5 + kx];
          a00 += wv * ld[ci][ry + ky][rx + kx];
          a01 += wv * ld[ci][ry + ky][rx + kx + 1];
          a10 += wv * ld[ci][ry + ky + 1][rx + kx];
          a11 += wv * ld[ci][ry + ky + 1][rx + kx + 1];
        }
      }
    }
    float m = fmaxf(fmaxf(a00, a01), fmaxf(a10, a11));
    p2[((b * 64 + cg * 16 + co) * 16 + ph) * 16 + pw] = m;
  }
}

// ---------------- K2: conv0 (y-half) + pool/argmax + s1 update + u write + s0 FC partial ----------------
// grid (64 b, 4 cg, 2 yh) = 512 blocks, 512 thr = 8 waves = kc(2) x qh(4).
// Wave: m=2 mt (cg's 32 co), n=2 nt (rows qh*2+nt of this y-half), K=32 (kc), all 25 taps.
// Staging: 12-row halo slab (rows yh*8-2..+9, y-pad baked in) of s2_t where
// s2_t = rho(p2 + sum 4 P1 partials) fused (t>0) or s2init (t=0).
// x-halo via zero row at pos 192 (single cndmask on pos; broadcast read).
// LDS plane = 193 rows x 72 ci-pitch; hi at 0, lo at 13896 halfs. Total 55584 B.
// s0 path: s0l = rho(sum 8 prev-slot partials + fcb); pacc[k] += s1old_j*fcw_kj reusing
// the epilogue's fcw loads; butterfly -> LDS -> 10 plain stores/block (no atomics).
__global__ __launch_bounds__(512, 4) void k_conv0F(
    const float* __restrict__ s2init, const float* __restrict__ p2,
    const float* __restrict__ P1, int fused,
    const _Float16* __restrict__ wA0h, const _Float16* __restrict__ wA0l,
    const float* __restrict__ b0,
    const float* __restrict__ s1old,
    const float* __restrict__ s0prevPart, float* __restrict__ s0curPart,
    const float* __restrict__ fcb,
    const float* __restrict__ fcw, float* __restrict__ s1new,
    unsigned* __restrict__ u) {
  __shared__ __align__(16) _Float16 sm[27792];   // 2 planes x [pos 193][ci 72] = 55584 B
  __shared__ float s0l[10];
  __shared__ float s0red[8][10];
  int b = blockIdx.x, cg = blockIdx.y, yh = blockIdx.z, tid = threadIdx.x;

  if (tid < 10) {   // s0_t = rho(sum of prev step's 8 slot partials + fcb); used only in epilogue
    float s = 0.f;
#pragma unroll
    for (int sl = 0; sl < 8; sl++) s += s0prevPart[(sl * 64 + b) * 10 + tid];
    s0l[tid] = rho_(s + fcb[tid]);
  }

  // stage 12-row slab: pos = ly*16+lx (ly 0..11 -> gy = yh*8-2+ly), 64 ci
  for (int i = tid; i < 12288; i += 512) {
    int ci = i / 192;
    int pos = i - ci * 192;
    int ly = pos >> 4, lx = pos & 15;
    int gy = yh * 8 - 2 + ly;
    float v = 0.f;
    if (gy >= 0 && gy < 16) {
      int gi = b * 16384 + ci * 256 + gy * 16 + lx;
      if (fused) {
        v = rho_(p2[gi] + P1[gi] + P1[gi + 1048576] + P1[gi + 2097152] + P1[gi + 3145728]);
      } else {
        v = s2init[gi];
      }
    }
    _Float16 h, l; split2(v, h, l);
    sm[pos * 72 + ci] = h;
    sm[13896 + pos * 72 + ci] = l;
  }
  // zero row (pos 192) in both planes: oob B-reads land here
  if (tid < 72) {
    sm[13824 + tid] = (_Float16)0.f;           // hi plane, pos 192
    sm[13896 + 13824 + tid] = (_Float16)0.f;   // lo plane, pos 192
  }
  __syncthreads();

  int lane = tid & 63, w = tid >> 6;
  int kc = w & 1, qh = w >> 1;
  int l16 = lane & 15, quad = lane >> 4;   // l16 = x within row

  f32x4 acch[2][2], accl[2][2];   // [nt][mt]
#pragma unroll
  for (int nt = 0; nt < 2; nt++)
#pragma unroll
    for (int mt = 0; mt < 2; mt++) {
      f32x4 z; z[0] = 0.f; z[1] = 0.f; z[2] = 0.f; z[3] = 0.f;
      accl[nt][mt] = z;
      if (kc == 0) {   // bias enters exactly once (kc=0 partial)
        int cb = cg * 32 + mt * 16 + quad * 4;
        f32x4 bi; bi[0] = b0[cb]; bi[1] = b0[cb + 1]; bi[2] = b0[cb + 2]; bi[3] = b0[cb + 3];
        acch[nt][mt] = bi;
      } else {
        acch[nt][mt] = z;
      }
    }

  const int bofs = kc * 32 + quad * 8;
  const int row0 = qh * 2 * 16;
  const int Abase = (kc * 128 + cg * 32 + l16) * 32 + quad * 8;

  half8 ahc[2], alc[2];
#pragma unroll
  for (int mt = 0; mt < 2; mt++)
    ahc[mt] = *(const half8*)(wA0h + Abase + mt * 512);

  for (int tap = 0; tap < 25; tap++) {
    // lo-plane A for this tap (first use is the 2nd MFMA; LDS wait covers it)
#pragma unroll
    for (int mt = 0; mt < 2; mt++)
      alc[mt] = *(const half8*)(wA0l + Abase + tap * 8192 + mt * 512);
    // prefetch next tap's hi-plane A (double-buffer across taps)
    half8 ahn[2];
    {
      int tn = (tap < 24) ? tap + 1 : tap;
#pragma unroll
      for (int mt = 0; mt < 2; mt++)
        ahn[mt] = *(const half8*)(wA0h + Abase + tn * 8192 + mt * 512);
    }
    int ky = tap / 5, kx = tap % 5;          // loop-uniform -> scalar
    int ix = l16 + kx - 2;
    bool oob = ((unsigned)ix > 15u);
    int ptap = ky * 16 + ix;
#pragma unroll
    for (int nt = 0; nt < 2; nt++) {
      int pos = row0 + nt * 16 + ptap;       // y-pad baked into slab
      if (oob) pos = 192;                    // zero row (broadcast read)
      const _Float16* bp = sm + pos * 72 + bofs;
      half8 bh = *(const half8*)bp;
      half8 bl = *(const half8*)(bp + 13896);
#pragma unroll
      for (int mt = 0; mt < 2; mt++) {
        acch[nt][mt] = MFMA_F16(ahc[mt], bh, acch[nt][mt]);
        accl[nt][mt] = MFMA_F16(alc[mt], bh, accl[nt][mt]);
        accl[nt][mt] = MFMA_F16(ahc[mt], bl, accl[nt][mt]);
      }
    }
#pragma unroll
    for (int mt = 0; mt < 2; mt++) ahc[mt] = ahn[mt];
  }

  // kc-combine via LDS C [co 32][130] (16640 B, reuses sm)
  __syncthreads();
  float* C = (float*)sm;
  if (kc == 0) {
#pragma unroll
    for (int nt = 0; nt < 2; nt++) {
      int pos = (qh * 2 + nt) * 16 + l16;   // 0..127 within half
#pragma unroll
      for (int mt = 0; mt < 2; mt++)
#pragma unroll
        for (int r = 0; r < 4; r++)
          C[(mt * 16 + quad * 4 + r) * 130 + pos] = acch[nt][mt][r] + LO_SCALE * accl[nt][mt][r];
    }
  }
  __syncthreads();
  if (kc == 1) {
#pragma unroll
    for (int nt = 0; nt < 2; nt++) {
      int pos = (qh * 2 + nt) * 16 + l16;
#pragma unroll
      for (int mt = 0; mt < 2; mt++)
#pragma unroll
        for (int r = 0; r < 4; r++) {
          int a = (mt * 16 + quad * 4 + r) * 130 + pos;
          C[a] += acch[nt][mt][r] + LO_SCALE * accl[nt][mt][r];
        }
    }
  }
  __syncthreads();

  // epilogue: 32 co x 32 windows (pooled rows yh*4..yh*4+3)
  float pacc[10];
#pragma unroll
  for (int k = 0; k < 10; k++) pacc[k] = 0.f;

  for (int it = 0; it < 2; it++) {
    int idx = it * 512 + tid;          // 1024 = 32 co x 32 windows
    int co = idx >> 5, win = idx & 31;
    int phl = win >> 3, pw = win & 7;
    int p0 = phl * 32 + pw * 2;
    float v0 = C[co * 130 + p0];
    float v1 = C[co * 130 + p0 + 1];
    float v2 = C[co * 130 + p0 + 16];
    float v3 = C[co * 130 + p0 + 17];
    float m0 = v0; int id = 0;
    if (v1 > m0) { m0 = v1; id = 1; }
    if (v2 > m0) { m0 = v2; id = 2; }
    if (v3 > m0) { m0 = v3; id = 3; }
    int co_g = cg * 32 + co;
    int ph = yh * 4 + phl;
    int j = co_g * 64 + ph * 8 + pw;
    float sv = s1old[b * 8192 + j];
    float a = m0;
#pragma unroll
    for (int k = 0; k < 10; k++) {
      float wv = fcw[k * 8192 + j];
      a += s0l[k] * wv;
      pacc[k] += sv * wv;      // s0 FC partial (reuses the fcw load)
    }
    s1new[b * 8192 + j] = rho_(a);
    _Float16 hh, hl; split2(sv, hh, hl);
    half2v hv; hv[0] = hh; hv[1] = hl;
    unsigned pk = __builtin_bit_cast(unsigned, hv);
    int bu = (b * 256 + ph * 32 + pw * 2) * 128 + co_g;   // u32 units: [b][pos 256][cp 128]
    u[bu]        = (id == 0) ? pk : 0u;
    u[bu + 128]  = (id == 1) ? pk : 0u;
    u[bu + 2048] = (id == 2) ? pk : 0u;
    u[bu + 2176] = (id == 3) ? pk : 0u;
  }

  // s0 partial: wave butterfly -> LDS -> 10 plain stores per block (no atomics)
#pragma unroll
  for (int k = 0; k < 10; k++) {
    float v = pacc[k];
#pragma unroll
    for (int off = 32; off > 0; off >>= 1) v += __shfl_xor(v, off);
    if (lane == 0) s0red[w][k] = v;
  }
  __syncthreads();
  if (tid < 10) {
    float s = s0red[0][tid] + s0red[1][tid] + s0red[2][tid] + s0red[3][tid]
            + s0red[4][tid] + s0red[5][tid] + s0red[6][tid] + s0red[7][tid];
    s0curPart[((cg * 2 + yh) * 64 + b) * 10 + tid] = s;
  }
}

// ---------------- K3: convT GEMM (cp-half x o-half x tap-group partial) ----------------
// zero row at pos 256 (both planes); A hi-plane double-buffered across taps.
// u staged packed: uint2 load (2 elems) + shift/or unpack + 2 ds_write_b32.
__global__ __launch_bounds__(512, 4) void k_convTg(
    const unsigned* __restrict__ u,
    const _Float16* __restrict__ wA1h, const _Float16* __restrict__ wA1l,
    float* __restrict__ P1) {
  __shared__ __align__(16) _Float16 sm[37008];
  int b = blockIdx.x, tid = threadIdx.x;
  int ks = blockIdx.y & 1;
  int oh = blockIdx.y >> 1;
  int tg = blockIdx.z;

  for (int i = tid; i < 8192; i += 512) {
    int pos = i >> 5, c2 = i & 31;
    uint2 vv = *(const uint2*)(u + b * 32768 + pos * 128 + ks * 64 + c2 * 2);
    unsigned hi = (vv.x & 0xffffu) | (vv.y << 16);
    unsigned lo = (vv.x >> 16) | (vv.y & 0xffff0000u);
    *(unsigned*)(sm + pos * 72 + c2 * 2) = hi;
    *(unsigned*)(sm + 18504 + pos * 72 + c2 * 2) = lo;
  }
  if (tid < 72) {
    sm[18432 + tid] = (_Float16)0.f;            // hi plane, pos 256
    sm[18504 + 18432 + tid] = (_Float16)0.f;    // lo plane, pos 256
  }
  __syncthreads();

  int lane = tid & 63, w = tid >> 6;
  int kc = w & 1, qh = w >> 1;
  int l16 = lane & 15, quad = lane >> 4;
  int wy = (l16 >> 1) & 1;
  int x_l = ((l16 >> 2) << 1) + (l16 & 1);

  f32x4 acch[4][2], accl[4][2];
#pragma unroll
  for (int nt = 0; nt < 4; nt++)
#pragma unroll
    for (int mt = 0; mt < 2; mt++) {
      f32x4 z; z[0] = 0.f; z[1] = 0.f; z[2] = 0.f; z[3] = 0.f;
      acch[nt][mt] = z; accl[nt][mt] = z;
    }

  const int bofs = kc * 32 + quad * 8;
  const int Abase = ((ks * 2 + kc) * 64 + oh * 32 + l16) * 32 + quad * 8;

  int yb[4], xb[4];   // loop-invariant spatial bases (+2 conv offset folded in)
#pragma unroll
  for (int nt = 0; nt < 4; nt++) {
    yb[nt] = qh * 4 + (nt >> 1) * 2 + wy + 2;
    xb[nt] = (nt & 1) * 8 + x_l + 2;
  }

  int tap0 = tg * 13, tap1 = tg ? 25 : 13;
  half8 ahc[2], alc[2];
#pragma unroll
  for (int mt = 0; mt < 2; mt++)
    ahc[mt] = *(const half8*)(wA1h + Abase + tap0 * 8192 + mt * 512);

  for (int tap = tap0; tap < tap1; tap++) {
#pragma unroll
    for (int mt = 0; mt < 2; mt++)
      alc[mt] = *(const half8*)(wA1l + Abase + tap * 8192 + mt * 512);
    half8 ahn[2];
    {
      int tn = (tap + 1 < tap1) ? tap + 1 : tap;
#pragma unroll
      for (int mt = 0; mt < 2; mt++)
        ahn[mt] = *(const half8*)(wA1h + Abase + tn * 8192 + mt * 512);
    }
    int ky = tap / 5, kx = tap % 5;
#pragma unroll
    for (int nt = 0; nt < 4; nt++) {
      int iy = yb[nt] - ky, ix = xb[nt] - kx;
      bool oob = ((unsigned)iy > 15u) || ((unsigned)ix > 15u);
      int pos = iy * 16 + ix;
      if (oob) pos = 256;                     // zero row (broadcast read)
      const _Float16* bp = sm + pos * 72 + bofs;
      half8 bh = *(const half8*)bp;
      half8 bl = *(const half8*)(bp + 18504);
#pragma unroll
      for (int mt = 0; mt < 2; mt++) {
        acch[nt][mt] = MFMA_F16(ahc[mt], bh, acch[nt][mt]);
        accl[nt][mt] = MFMA_F16(alc[mt], bh, accl[nt][mt]);
        accl[nt][mt] = MFMA_F16(ahc[mt], bl, accl[nt][mt]);
      }
    }
#pragma unroll
    for (int mt = 0; mt < 2; mt++) ahc[mt] = ahn[mt];
  }

  __syncthreads();
  float* C = (float*)sm;   // [o 32][260]
  if (kc == 0) {
#pragma unroll
    for (int nt = 0; nt < 4; nt++) {
      int pos = (qh * 4 + (nt >> 1) * 2 + wy) * 16 + (nt & 1) * 8 + x_l;
#pragma unroll
      for (int mt = 0; mt < 2; mt++)
#pragma unroll
        for (int r = 0; r < 4; r++)
          C[(mt * 16 + quad * 4 + r) * 260 + pos] = acch[nt][mt][r] + LO_SCALE * accl[nt][mt][r];
    }
  }
  __syncthreads();
  if (kc == 1) {
#pragma unroll
    for (int nt = 0; nt < 4; nt++) {
      int pos = (qh * 4 + (nt >> 1) * 2 + wy) * 16 + (nt & 1) * 8 + x_l;
#pragma unroll
      for (int mt = 0; mt < 2; mt++)
#pragma unroll
        for (int r = 0; r < 4; r++) {
          int a = (mt * 16 + quad * 4 + r) * 260 + pos;
          C[a] += acch[nt][mt][r] + LO_SCALE * accl[nt][mt][r];
        }
    }
  }
  __syncthreads();

  float* op = P1 + (tg * 2 + ks) * 1048576 + (b * 64 + oh * 32) * 256;
  for (int m = tid; m < 8192; m += 512) {
    int o = m >> 8, pos = m & 255;
    op[o * 256 + pos] = C[o * 260 + pos];
  }
}

// ---------------- K3b: s2-combine + s1 copy + s0 finalize (t=6 snapshot, t=9 final) ----------------
// blocks 0..1023: s2 = rho(p2 + P1[0..3]) (+ blocks 0-2: s0 = rho(sum 8 partials + fcb));
// blocks 1024..1535: s1 float4 copy.
__global__ __launch_bounds__(256) void k_cTcomb(
    const float* __restrict__ p2, const float* __restrict__ P1,
    float* __restrict__ out_s2,
    const float* __restrict__ s1src, float* __restrict__ out_s1,
    const float* __restrict__ s0part, const float* __restrict__ fcb,
    float* __restrict__ out_s0) {
  int blk = blockIdx.x, tid = threadIdx.x;
  if (blk < 1024) {
    int i = blk * 256 + tid;   // over 262144 float4s
    float4 p = ((const float4*)p2)[i];
    float4 a0 = ((const float4*)P1)[i];
    float4 a1 = ((const float4*)(P1 + 1048576))[i];
    float4 a2 = ((const float4*)(P1 + 2097152))[i];
    float4 a3 = ((const float4*)(P1 + 3145728))[i];
    float4 o;
    o.x = rho_(p.x + a0.x + a1.x + a2.x + a3.x);
    o.y = rho_(p.y + a0.y + a1.y + a2.y + a3.y);
    o.z = rho_(p.z + a0.z + a1.z + a2.z + a3.z);
    o.w = rho_(p.w + a0.w + a1.w + a2.w + a3.w);
    ((float4*)out_s2)[i] = o;
    if (i < 640) {
      int bb = i / 10, k = i - bb * 10;
      float s = 0.f;
#pragma unroll
      for (int sl = 0; sl < 8; sl++) s += s0part[(sl * 64 + bb) * 10 + k];
      out_s0[i] = rho_(s + fcb[k]);
    }
  } else {
    int i2 = (blk - 1024) * 256 + tid;   // over 131072 float4s (2 MB)
    ((float4*)out_s1)[i2] = ((const float4*)s1src)[i2];
  }
}

extern "C" void kernel_launch(void* const* d_in, const int* in_sizes, int n_in,
                              void* d_out, int out_size, void* d_ws, size_t ws_size,
                              hipStream_t stream) {
  const float* data   = (const float*)d_in[0];
  const float* s0init = (const float*)d_in[1];   // zeros
  const float* s1init = (const float*)d_in[2];   // zeros
  const float* s2init = (const float*)d_in[3];   // zeros (t=0 conv0 input)
  const float* conv0w = (const float*)d_in[4];
  const float* conv0b = (const float*)d_in[5];
  const float* conv1w = (const float*)d_in[6];
  const float* conv1b = (const float*)d_in[7];
  const float* fcw    = (const float*)d_in[8];
  const float* fcb    = (const float*)d_in[9];
  (void)s0init;

  // workspace (~35 MB)
  float* p = (float*)d_ws;
  float* s0part = p;                         p += 10240;     // 2 bufs x [slot 8][b 64][10]
  float* s1buf[2] = {p, p + 524288};         p += 1048576;
  float* p2 = p;                             p += 1048576;
  float* P1 = p;                             p += 4194304;   // 4 x 1M convT partials
  unsigned* u = (unsigned*)p;                p += 2097152;   // packed hi|lo [b][pos 256][cp 128]
  _Float16* hq = (_Float16*)p;
  _Float16* wA0h = hq;                       hq += 204800;
  _Float16* wA0l = hq;                       hq += 204800;
  _Float16* wA1h = hq;                       hq += 204800;
  _Float16* wA1l = hq;                       hq += 204800;

  k_wprep<<<800, 256, 0, stream>>>(conv0w, fcb, wA0h, wA0l, wA1h, wA1l, s0part);
  k_p2<<<dim3(64, 4), 256, 0, stream>>>(data, conv1w, conv1b, p2);

  const float* s1o = s1init;
  float* outp = (float*)d_out;

  for (int t = 0; t < 10; t++) {
    int nb = t & 1;
    float* s1w = s1buf[nb];

    // conv0(s2_t) [s2_t = rho(p2+sumP1) fused for t>0] + pool/argmax;
    // s1_new = rho(p1 + fc^T(s0_t)); u = split(unpool(s1_old, idx));
    // s0 FC partials -> s0part buf[(t+1)&1] (s0_{t+1} = rho(sum slots + fcb))
    k_conv0F<<<dim3(64, 4, 2), 512, 0, stream>>>(s2init, p2, P1, (t > 0),
                                                 wA0h, wA0l, conv0b,
                                                 s1o,
                                                 s0part + (t & 1) * 5120,
                                                 s0part + ((t + 1) & 1) * 5120,
                                                 fcb, fcw, s1w, u);
    // convT partials (consumed by next step's conv0F staging, or cTcomb at t=6/9)
    k_convTg<<<dim3(64, 4, 2), 512, 0, stream>>>(u, wA1h, wA1l, P1);

    s1o = s1w;

    if (t == 6) {   // PRED_T snapshot: s0_7, s1_7, s2_7 = rho(p2+sumP1) -> d_out directly
      k_cTcomb<<<1536, 256, 0, stream>>>(p2, P1, outp + 2098432,
                                         s1o, outp + 1574144,
                                         s0part + 5120, fcb, outp + 1573504);
    }
  }

  // final states: s0_10 (partials in buf[0]), s1_10, s2_10 -> d_out
  k_cTcomb<<<1536, 256, 0, stream>>>(p2, P1, outp + 524928,
                                     s1o, outp + 640,
                                     s0part, fcb, outp + 0);
}